// Round 2
// baseline (3725.904 us; speedup 1.0000x reference)
//
#include <hip/hip_runtime.h>
#include <hip/hip_bf16.h>

// CharNNClassifier: out = (LSTM(emb[x]) last h) @ W_out^T + b_out
// B=256 S=512 V=256 E=128 H=256 4H=1024 O=128, fp32 in/out.
//
// R2 design: NO cross-workgroup communication.
//  - 16 wgs x 512 threads (8 waves, 2 waves/SIMD, 256-VGPR budget).
//  - Each wg owns one 16-row batch stripe and holds the FULL W_hh as fp16
//    MFMA B-fragments in VGPRs (512KB/wg / 512 lanes = 128 VGPR/lane).
//  - Per step: gates[16,1024] = h[16,256] @ W_hh^T via 512x
//    mfma_f32_16x16x32_f16 per wg (64/wave), h double-buffered in LDS,
//    ONE __syncthreads() per step. c stays fp32 in registers.
//  - T2[v][unit][gate] interleaved so the input-gate gather is one float4.

typedef _Float16 f16x8 __attribute__((ext_vector_type(8)));
typedef float    f32x4 __attribute__((ext_vector_type(4)));

#define B_  256
#define S_  512
#define V_  256
#define E_  128
#define H_  256
#define G4_ 1024
#define O_  128

// ws layout (bytes)
#define T_OFF     0u                      // T2: 256*1024*4 = 1 MiB
#define HLAST_OFF (1u << 20)              // hlast: 256*256*4 = 256 KiB

// ---------------------------------------------------------------- K1: table
// T2[v][unit][t] = (W_ih @ emb[v])[t*256+unit] + b_ih[..] + b_hh[..]
__global__ void build_table(const float* __restrict__ emb,
                            const float* __restrict__ W_ih,
                            const float* __restrict__ b_ih,
                            const float* __restrict__ b_hh,
                            float* __restrict__ T2) {
    const int v   = blockIdx.x;   // vocab id
    const int tid = threadIdx.x;  // 256 threads = unit

    __shared__ float e[E_];
    if (tid < E_) e[tid] = emb[v * E_ + tid];
    __syncthreads();

#pragma unroll
    for (int t = 0; t < 4; ++t) {
        const int g = t * 256 + tid;
        const float4* wp = (const float4*)(W_ih + g * E_);
        float acc = 0.f;
#pragma unroll
        for (int i = 0; i < E_ / 4; ++i) {
            float4 w = wp[i];
            acc += w.x * e[4*i] + w.y * e[4*i+1] + w.z * e[4*i+2] + w.w * e[4*i+3];
        }
        T2[v * G4_ + tid * 4 + t] = acc + b_ih[g] + b_hh[g];
    }
}

// ------------------------------------------------------------ K2: recurrence
__device__ __forceinline__ float sig_fast(float x) {
    x = fminf(fmaxf(x, -30.f), 30.f);
    float t = __builtin_amdgcn_exp2f(-1.4426950408889634f * x);
    return __builtin_amdgcn_rcpf(1.f + t);
}
__device__ __forceinline__ float tanh_fast(float x) {
    x = fminf(fmaxf(x, -15.f), 15.f);
    float t = __builtin_amdgcn_exp2f(-2.8853900817779268f * x);  // e^{-2x}
    return (1.f - t) * __builtin_amdgcn_rcpf(1.f + t);
}

#define HSTRIDE 264   // fp16 elements per LDS h row (256 + 8 pad: breaks 16-way bank aliasing)

__launch_bounds__(512, 2)
__global__ void lstm_persistent(const int* __restrict__ x,
                                const float* __restrict__ W_hh,
                                const float* __restrict__ T2,
                                float* __restrict__ hlast) {
    const int tid    = threadIdx.x;
    const int wv     = tid >> 6;     // wave 0..7
    const int l      = tid & 63;
    const int l15    = l & 15;
    const int quad   = l >> 4;       // 0..3
    const int stripe = blockIdx.x;   // 0..15, batch rows [stripe*16, stripe*16+16)

    // ---- prologue: full W_hh -> fp16 MFMA B-fragments in VGPRs.
    // n-tile j covers gate cols [j*128 + wv*16, +16); col n = base + l15.
    // B-frag (16x16x32): lane holds B[k = kt*32 + quad*8 + i][n] = W_hh[n][k].
    // j = 2*t + p  =>  gate type t = j>>1, unit u = wv*16 + p*128 + l15.
    f16x8 wfrag[8][8];
#pragma unroll
    for (int j = 0; j < 8; ++j) {
        const int col = j * 128 + wv * 16 + l15;     // W_hh row (= gate col)
        const float* wr = W_hh + col * H_;
#pragma unroll
        for (int kt = 0; kt < 8; ++kt) {
            const float4* wp = (const float4*)(wr + kt * 32 + quad * 8);
            float4 w0 = wp[0];
            float4 w1 = wp[1];
            wfrag[j][kt] = (f16x8){
                (_Float16)w0.x, (_Float16)w0.y, (_Float16)w0.z, (_Float16)w0.w,
                (_Float16)w1.x, (_Float16)w1.y, (_Float16)w1.z, (_Float16)w1.w};
        }
    }

    // h double buffer in LDS: h for step s lives in hbuf[s&1].
    __shared__ __align__(16) _Float16 hbuf[2][16][HSTRIDE];

    float c[2][4] = {{0.f, 0.f, 0.f, 0.f}, {0.f, 0.f, 0.f, 0.f}};
    const int row0 = stripe * 16 + quad * 4;   // this lane's 4 C-rows

    for (int s = 0; s < S_; ++s) {
        // x for this lane's 4 rows (L1-resident; same line across steps)
        int vv[4];
#pragma unroll
        for (int r = 0; r < 4; ++r) vv[r] = x[(row0 + r) * S_ + s];

        f32x4 acc[8];
#pragma unroll
        for (int j = 0; j < 8; ++j) acc[j] = (f32x4){0.f, 0.f, 0.f, 0.f};

        if (s > 0) {
            // A-frags: lane holds A[m = l15][k = kt*32 + quad*8 + i]
            const _Float16* hb = &hbuf[(s - 1) & 1][0][0] + l15 * HSTRIDE + quad * 8;
            f16x8 a[8];
#pragma unroll
            for (int kt = 0; kt < 8; ++kt)
                a[kt] = *(const f16x8*)(hb + kt * 32);
#pragma unroll
            for (int j = 0; j < 8; ++j) {
#pragma unroll
                for (int kt = 0; kt < 8; ++kt)
                    acc[j] = __builtin_amdgcn_mfma_f32_16x16x32_f16(
                        a[kt], wfrag[j][kt], acc[j], 0, 0, 0);
            }
        }

        // input contribution (fp32 float4 gather) + nonlinearities + h publish
        // C/D layout: col = l15 (-> unit), row = quad*4 + r  (verified R1)
#pragma unroll
        for (int p = 0; p < 2; ++p) {
            const int u = wv * 16 + p * 128 + l15;   // hidden unit
#pragma unroll
            for (int r = 0; r < 4; ++r) {
                const float4 tv = *(const float4*)(T2 + (size_t)vv[r] * G4_ + u * 4);
                float gi = sig_fast (acc[0 + p][r] + tv.x);
                float gf = sig_fast (acc[2 + p][r] + tv.y);
                float gg = tanh_fast(acc[4 + p][r] + tv.z);
                float go = sig_fast (acc[6 + p][r] + tv.w);
                float cc = gf * c[p][r] + gi * gg;
                c[p][r]  = cc;
                float hv = go * tanh_fast(cc);
                if (s < S_ - 1) {
                    hbuf[s & 1][quad * 4 + r][u] = (_Float16)hv;
                } else {
                    hlast[(row0 + r) * H_ + u] = hv;   // fp32 for the head
                }
            }
        }
        // one barrier per step: guarantees (a) this step's h visible before
        // next step's reads, (b) buf[s&1] reads from step s+1 complete before
        // step s+2 overwrites it.
        __syncthreads();
    }
}

// ---------------------------------------------------------------- K3: head
__global__ void out_kernel(const float* __restrict__ hlast,
                           const float* __restrict__ W_out,
                           const float* __restrict__ b_out,
                           float* __restrict__ out) {
    const int b = blockIdx.x;    // 256
    const int o = threadIdx.x;   // 128
    __shared__ float hl[H_];
    hl[o]       = hlast[b * H_ + o];
    hl[o + 128] = hlast[b * H_ + o + 128];
    __syncthreads();
    const float4* wp = (const float4*)(W_out + o * H_);
    float acc = 0.f;
#pragma unroll
    for (int i = 0; i < H_ / 4; ++i) {
        float4 w = wp[i];
        acc += w.x * hl[4*i] + w.y * hl[4*i+1] + w.z * hl[4*i+2] + w.w * hl[4*i+3];
    }
    out[b * O_ + o] = acc + b_out[o];
}

// ----------------------------------------------------------------- launcher
extern "C" void kernel_launch(void* const* d_in, const int* in_sizes, int n_in,
                              void* d_out, int out_size, void* d_ws, size_t ws_size,
                              hipStream_t stream) {
    const int*   x     = (const int*)  d_in[0];
    const float* emb   = (const float*)d_in[1];
    const float* W_ih  = (const float*)d_in[2];
    const float* W_hh  = (const float*)d_in[3];
    const float* b_ih  = (const float*)d_in[4];
    const float* b_hh  = (const float*)d_in[5];
    const float* W_out = (const float*)d_in[6];
    const float* b_out = (const float*)d_in[7];
    float* out = (float*)d_out;

    char* ws = (char*)d_ws;
    float* T2    = (float*)(ws + T_OFF);
    float* hlast = (float*)(ws + HLAST_OFF);

    build_table<<<dim3(V_), dim3(256), 0, stream>>>(emb, W_ih, b_ih, b_hh, T2);
    lstm_persistent<<<dim3(16), dim3(512), 0, stream>>>(x, W_hh, T2, hlast);
    out_kernel<<<dim3(B_), dim3(O_), 0, stream>>>(hlast, W_out, b_out, out);
}

// Round 3
// 1810.057 us; speedup vs baseline: 2.0584x; 2.0584x over previous
//
#include <hip/hip_runtime.h>
#include <hip/hip_bf16.h>

// CharNNClassifier: out = (LSTM(emb[x]) last h) @ W_out^T + b_out
// B=256 S=512 V=256 E=128 H=256 4H=1024 O=128, fp32 in/out.
//
// R3 design: one wg per batch stripe, W_hh split register/LDS.
//  - 16 wgs x 512 threads (8 waves, 2 waves/SIMD, 256 unified regs/lane).
//  - W_hh fp16 = 512 KB/CU = register file size, so it CANNOT be all-reg
//    (R2's scratch-spill lesson). Split: 48 frags/lane in VGPRs (384 KB/wg)
//    + 16 frags/lane in LDS (128 KB). h double-buffer in LDS (16.5 KB).
//    Total LDS 144.5 KB (gfx950 has 160 KB/CU).
//  - Per step: 512x mfma_f32_16x16x32_f16, kt-outer/j-inner so A-frags
//    stream (8 live regs), ONE __syncthreads per step.
//  - T2 gate table packed fp16x4 per (v,unit): one 8B load per (r,p).

typedef _Float16 f16x8 __attribute__((ext_vector_type(8)));
typedef _Float16 f16x4 __attribute__((ext_vector_type(4)));
typedef float    f32x4 __attribute__((ext_vector_type(4)));

#define B_  256
#define S_  512
#define V_  256
#define E_  128
#define H_  256
#define G4_ 1024
#define O_  128

// ws layout (bytes)
#define T_OFF     0u              // T2h: 256*256*4 fp16 = 512 KiB
#define HLAST_OFF (1u << 19)      // hlast: 256*256*4B = 256 KiB

// ---------------------------------------------------------------- K1: table
// T2h[v][unit] = fp16x4 {i,f,g,o} pre-activations from the embedding path.
__global__ void build_table(const float* __restrict__ emb,
                            const float* __restrict__ W_ih,
                            const float* __restrict__ b_ih,
                            const float* __restrict__ b_hh,
                            _Float16* __restrict__ T2h) {
    const int v   = blockIdx.x;   // vocab id
    const int tid = threadIdx.x;  // 256 threads = hidden unit

    __shared__ float e[E_];
    if (tid < E_) e[tid] = emb[v * E_ + tid];
    __syncthreads();

    f16x4 tv;
#pragma unroll
    for (int t = 0; t < 4; ++t) {
        const int g = t * 256 + tid;
        const float4* wp = (const float4*)(W_ih + g * E_);
        float acc = 0.f;
#pragma unroll
        for (int i = 0; i < E_ / 4; ++i) {
            float4 w = wp[i];
            acc += w.x * e[4*i] + w.y * e[4*i+1] + w.z * e[4*i+2] + w.w * e[4*i+3];
        }
        tv[t] = (_Float16)(acc + b_ih[g] + b_hh[g]);
    }
    *(f16x4*)(T2h + ((size_t)v * 256 + tid) * 4) = tv;
}

// ------------------------------------------------------------ K2: recurrence
__device__ __forceinline__ float sig_fast(float x) {
    x = fminf(fmaxf(x, -30.f), 30.f);
    float t = __builtin_amdgcn_exp2f(-1.4426950408889634f * x);
    return __builtin_amdgcn_rcpf(1.f + t);
}
__device__ __forceinline__ float tanh_fast(float x) {
    x = fminf(fmaxf(x, -15.f), 15.f);
    float t = __builtin_amdgcn_exp2f(-2.8853900817779268f * x);  // e^{-2x}
    return (1.f - t) * __builtin_amdgcn_rcpf(1.f + t);
}

#define HSTRIDE 264   // fp16 per LDS h row: 256 + 8 pad (2-way banks = free)

__launch_bounds__(512, 2)
__global__ void lstm_persistent(const int* __restrict__ x,
                                const float* __restrict__ W_hh,
                                const _Float16* __restrict__ T2h,
                                float* __restrict__ hlast) {
    const int tid    = threadIdx.x;
    const int wv     = tid >> 6;     // wave 0..7
    const int l      = tid & 63;
    const int l15    = l & 15;
    const int quad   = l >> 4;       // 0..3
    const int stripe = blockIdx.x;   // batch rows [stripe*16, +16)

    // LDS: 128 KB weights (kt 0..1 of every (wave,j) n-tile) + h dbuf.
    __shared__ __align__(16) _Float16 wlds[8][8][2][512];
    __shared__ __align__(16) _Float16 hbuf[2][16][HSTRIDE];

    // ---- prologue: W_hh -> fp16 MFMA B-fragments (regs for kt 2..7,
    // LDS for kt 0..1).  col n = j*128 + wv*16 + l15; k = kt*32 + quad*8 + i.
    // B[k][n] = W_hh[n][k].
    f16x8 wreg[8][6];
#pragma unroll
    for (int j = 0; j < 8; ++j) {
        const float* wr = W_hh + (j * 128 + wv * 16 + l15) * H_ + quad * 8;
#pragma unroll
        for (int kt = 0; kt < 8; ++kt) {
            const float4* wp = (const float4*)(wr + kt * 32);
            float4 w0 = wp[0];
            float4 w1 = wp[1];
            f16x8 f = (f16x8){
                (_Float16)w0.x, (_Float16)w0.y, (_Float16)w0.z, (_Float16)w0.w,
                (_Float16)w1.x, (_Float16)w1.y, (_Float16)w1.z, (_Float16)w1.w};
            if (kt < 2)
                *(f16x8*)&wlds[wv][j][kt][(size_t)l * 8] = f;
            else
                wreg[j][kt - 2] = f;
        }
    }
    __syncthreads();

    float c[2][4] = {{0.f, 0.f, 0.f, 0.f}, {0.f, 0.f, 0.f, 0.f}};
    const int row0 = stripe * 16 + quad * 4;   // this lane's 4 C-rows

    for (int s = 0; s < S_; ++s) {
        // x indices for this lane's 4 rows (independent of h: issue first)
        int vv[4];
#pragma unroll
        for (int r = 0; r < 4; ++r) vv[r] = x[(row0 + r) * S_ + s];

        f32x4 acc[8];
#pragma unroll
        for (int j = 0; j < 8; ++j) acc[j] = (f32x4){0.f, 0.f, 0.f, 0.f};

        if (s > 0) {
            // A-frag row m = l15, k = kt*32 + quad*8 + i, streamed kt-outer
            const _Float16* hb = &hbuf[(s - 1) & 1][0][0] + l15 * HSTRIDE + quad * 8;
#pragma unroll
            for (int kt = 0; kt < 8; ++kt) {
                f16x8 a = *(const f16x8*)(hb + kt * 32);
                if (kt < 2) {
#pragma unroll
                    for (int j = 0; j < 8; ++j) {
                        f16x8 b = *(const f16x8*)&wlds[wv][j][kt][(size_t)l * 8];
                        acc[j] = __builtin_amdgcn_mfma_f32_16x16x32_f16(
                            a, b, acc[j], 0, 0, 0);
                    }
                } else {
#pragma unroll
                    for (int j = 0; j < 8; ++j)
                        acc[j] = __builtin_amdgcn_mfma_f32_16x16x32_f16(
                            a, wreg[j][kt - 2], acc[j], 0, 0, 0);
                }
            }
        }

        // epilogue per 128-unit half to bound live registers.
        // C/D layout: col = l15 (unit low bits), row = quad*4 + r.
        // acc[j] covers gate col j*128 + wv*16 + l15  =>  t = j>>1... with
        // j = 2*t + p:  gate t, unit u = p*128 + wv*16 + l15.
#pragma unroll
        for (int p = 0; p < 2; ++p) {
            const int u = wv * 16 + p * 128 + l15;   // hidden unit
#pragma unroll
            for (int r = 0; r < 4; ++r) {
                f16x4 tv = *(const f16x4*)(T2h + ((size_t)vv[r] * 256 + u) * 4);
                float gi = sig_fast (acc[0 + p][r] + (float)tv[0]);
                float gf = sig_fast (acc[2 + p][r] + (float)tv[1]);
                float gg = tanh_fast(acc[4 + p][r] + (float)tv[2]);
                float go = sig_fast (acc[6 + p][r] + (float)tv[3]);
                float cc = gf * c[p][r] + gi * gg;
                c[p][r]  = cc;
                float hv = go * tanh_fast(cc);
                if (s < S_ - 1) {
                    hbuf[s & 1][quad * 4 + r][u] = (_Float16)hv;
                } else {
                    hlast[(row0 + r) * H_ + u] = hv;   // fp32 for the head
                }
            }
        }
        // one barrier per step: h_s visible before step s+1 reads it, and
        // hbuf[s&1] reads (step s+1) complete before step s+2 overwrites.
        __syncthreads();
    }
}

// ---------------------------------------------------------------- K3: head
__global__ void out_kernel(const float* __restrict__ hlast,
                           const float* __restrict__ W_out,
                           const float* __restrict__ b_out,
                           float* __restrict__ out) {
    const int b = blockIdx.x;    // 256
    const int o = threadIdx.x;   // 128
    __shared__ float hl[H_];
    hl[o]       = hlast[b * H_ + o];
    hl[o + 128] = hlast[b * H_ + o + 128];
    __syncthreads();
    const float4* wp = (const float4*)(W_out + o * H_);
    float acc = 0.f;
#pragma unroll
    for (int i = 0; i < H_ / 4; ++i) {
        float4 w = wp[i];
        acc += w.x * hl[4*i] + w.y * hl[4*i+1] + w.z * hl[4*i+2] + w.w * hl[4*i+3];
    }
    out[b * O_ + o] = acc + b_out[o];
}

// ----------------------------------------------------------------- launcher
extern "C" void kernel_launch(void* const* d_in, const int* in_sizes, int n_in,
                              void* d_out, int out_size, void* d_ws, size_t ws_size,
                              hipStream_t stream) {
    const int*   x     = (const int*)  d_in[0];
    const float* emb   = (const float*)d_in[1];
    const float* W_ih  = (const float*)d_in[2];
    const float* W_hh  = (const float*)d_in[3];
    const float* b_ih  = (const float*)d_in[4];
    const float* b_hh  = (const float*)d_in[5];
    const float* W_out = (const float*)d_in[6];
    const float* b_out = (const float*)d_in[7];
    float* out = (float*)d_out;

    char* ws = (char*)d_ws;
    _Float16* T2h   = (_Float16*)(ws + T_OFF);
    float*    hlast = (float*)(ws + HLAST_OFF);

    build_table<<<dim3(V_), dim3(256), 0, stream>>>(emb, W_ih, b_ih, b_hh, T2h);
    lstm_persistent<<<dim3(16), dim3(512), 0, stream>>>(x, W_hh, T2h, hlast);
    out_kernel<<<dim3(B_), dim3(O_), 0, stream>>>(hlast, W_out, b_out, out);
}